// Round 3
// baseline (192.755 us; speedup 1.0000x reference)
//
#include <hip/hip_runtime.h>
#include <hip/hip_bf16.h>
#include <stdint.h>

// SimCLR loss, B=4096, D=256, T=0.1.
// loss = (1/2B) * sum_i [ log(sum_{j!=i} exp(sim_ij)) - sim_{i,pair(i)} ]
// sim in [-10,10] => no max-subtraction needed.
// Symmetric Gram: lower-triangle tiles only; off-diag tiles add row sums
// to rowsum[i] and col sums to rowsum[j].
// Strip structure: block owns row-strip bi and <=4 bj tiles. A fragments
// (64 rows x K=256 per wave) live in VGPRs for the whole block; B streams
// through double-buffered LDS via global_load_lds.

#define BROWS 4096
#define NROWS 8192   // 2B
#define DDIM  256
#define TINV  10.0f
#define EPSN  1e-8f

typedef __bf16 bf16;
typedef bf16  bf16x4 __attribute__((ext_vector_type(4)));
typedef bf16  bf16x8 __attribute__((ext_vector_type(8)));
typedef float f32x4  __attribute__((ext_vector_type(4)));

// ------- prep: norms + bf16 unit rows + positive logits + zeroing ----------
__global__ __launch_bounds__(256) void prep_kernel(
    const float* __restrict__ z1, const float* __restrict__ z2,
    bf16* __restrict__ zn, float* __restrict__ pos,
    float* __restrict__ rowsum, float* __restrict__ out) {
  int t = threadIdx.x;
  int i    = blockIdx.x * 4 + (t >> 6);
  int lane = t & 63;
  if (blockIdx.x < 32) rowsum[blockIdx.x * 256 + t] = 0.f;   // zero 8192 f32
  if (blockIdx.x == 32 && t == 0) out[0] = 0.f;              // zero output

  float4 a = ((const float4*)(z1 + (size_t)i * DDIM))[lane];
  float4 b = ((const float4*)(z2 + (size_t)i * DDIM))[lane];
  float s1 = a.x*a.x + a.y*a.y + a.z*a.z + a.w*a.w;
  float s2 = b.x*b.x + b.y*b.y + b.z*b.z + b.w*b.w;
  float dt = a.x*b.x + a.y*b.y + a.z*b.z + a.w*b.w;
  #pragma unroll
  for (int off = 32; off; off >>= 1) {
    s1 += __shfl_xor(s1, off, 64);
    s2 += __shfl_xor(s2, off, 64);
    dt += __shfl_xor(dt, off, 64);
  }
  float n1 = fmaxf(sqrtf(s1), EPSN), n2 = fmaxf(sqrtf(s2), EPSN);
  float i1 = 1.0f / n1, i2 = 1.0f / n2;
  if (lane == 0) pos[i] = dt * i1 * i2 * TINV;
  bf16x4 o1, o2;
  o1[0] = (bf16)(a.x*i1); o1[1] = (bf16)(a.y*i1);
  o1[2] = (bf16)(a.z*i1); o1[3] = (bf16)(a.w*i1);
  o2[0] = (bf16)(b.x*i2); o2[1] = (bf16)(b.y*i2);
  o2[2] = (bf16)(b.z*i2); o2[3] = (bf16)(b.w*i2);
  *(bf16x4*)(zn + (size_t)i * DDIM + lane * 4) = o1;
  *(bf16x4*)(zn + (size_t)(i + BROWS) * DDIM + lane * 4) = o2;
}

// ---------------- async global->LDS, 16B ----------------------------------
__device__ __forceinline__ void async16(const bf16* g, bf16* l) {
  __builtin_amdgcn_global_load_lds(
      (const __attribute__((address_space(1))) unsigned int*)g,
      (__attribute__((address_space(3))) unsigned int*)l,
      16, 0, 0);
}

#define TM   128
#define BKC  64                       // K per staged chunk
#define NTILE (NROWS / TM)            // 64 strips

// grid: (16, 64). block (g, bi) handles tiles (bi, bj) for bj in
// [4g, min(4g+3, bi)]; blocks with 4g > bi exit immediately.
__global__ __launch_bounds__(256, 2) void simexp_kernel(
    const bf16* __restrict__ zn, float* __restrict__ rowsum) {
  __shared__ __align__(16) bf16 ldsB[2][TM * BKC];   // 2 x 16 KB

  const int bi = blockIdx.y, g = blockIdx.x;
  const int bj0 = g * 4;
  if (bj0 > bi) return;
  const int bj1 = (bj0 + 3 < bi) ? (bj0 + 3) : bi;
  const int nchunks = (bj1 - bj0 + 1) * 4;

  const int t = threadIdx.x;
  const int wave = t >> 6, lane = t & 63;
  const int wr = wave >> 1, wc = wave & 1;
  const int quad = lane >> 4, l15 = lane & 15;
  const int rowA0 = bi * TM;

  // ---- A: full K resident in VGPRs (32 x bf16x8 = 128 regs per lane) ----
  // af[mi][c] = A[rowA0 + wr*64 + mi*16 + l15][c*32 + quad*8 .. +8]
  bf16x8 af[4][8];
  {
    const bf16* aptr = zn + (size_t)(rowA0 + wr * 64 + l15) * DDIM + quad * 8;
    #pragma unroll
    for (int mi = 0; mi < 4; ++mi)
      #pragma unroll
      for (int c = 0; c < 8; ++c)
        af[mi][c] = *(const bf16x8*)(aptr + (size_t)mi * 16 * DDIM + c * 32);
  }

  f32x4 acc[4][4] = {};
  float rs[4][4] = {};                 // strip row-sum accumulators

  // stage chunk s (tile bj0 + s/4, K-chunk s%4) into ldsB[buf]
  auto stage = [&](int s, int buf) {
    int bj = bj0 + (s >> 2), kc = s & 3;
    const bf16* base = zn + (size_t)(bj * TM) * DDIM + kc * BKC;
    #pragma unroll
    for (int p = 0; p < 4; ++p) {
      int c = p * 256 + t;
      int row = c >> 3, c8 = c & 7;
      int gc8 = c8 ^ (row & 7);              // XOR swizzle in global addr
      async16(base + (size_t)row * DDIM + gc8 * 8, &ldsB[buf][c * 8]);
    }
  };

  stage(0, 0);
  for (int s = 0; s < nchunks; ++s) {
    __syncthreads();                          // drains DMA for ldsB[s&1]
    if (s + 1 < nchunks) stage(s + 1, (s + 1) & 1);

    const bf16* bb = ldsB[s & 1];
    const int kc = s & 3;
    #pragma unroll
    for (int kk = 0; kk < 2; ++kk) {          // two 32-K subchunks
      const int kc8 = kk * 4 + quad;
      bf16x8 bg[4];
      #pragma unroll
      for (int nj = 0; nj < 4; ++nj) {
        int row = wc * 64 + nj * 16 + l15;
        int sc8 = kc8 ^ (row & 7);
        bg[nj] = *(const bf16x8*)&bb[(row * 8 + sc8) * 8];
      }
      #pragma unroll
      for (int mi = 0; mi < 4; ++mi)
        #pragma unroll
        for (int nj = 0; nj < 4; ++nj)
          acc[mi][nj] = __builtin_amdgcn_mfma_f32_16x16x32_bf16(
              af[mi][kc * 2 + kk], bg[nj], acc[mi][nj], 0, 0, 0);
    }

    if ((s & 3) == 3) {                       // tile finished: epilogue
      const int bj = bj0 + (s >> 2);
      const int rowB0 = bj * TM;
      float cs[4] = {0.f, 0.f, 0.f, 0.f};
      #pragma unroll
      for (int mi = 0; mi < 4; ++mi)
        #pragma unroll
        for (int nj = 0; nj < 4; ++nj) {
          int gj = rowB0 + wc * 64 + nj * 16 + l15;
          #pragma unroll
          for (int r = 0; r < 4; ++r) {
            int gi = rowA0 + wr * 64 + mi * 16 + quad * 4 + r;
            float e = (gi == gj) ? 0.f : __expf(acc[mi][nj][r] * TINV);
            rs[mi][r] += e;
            cs[nj] += e;
            acc[mi][nj][r] = 0.f;             // reset for next tile
          }
        }
      if (bj != bi) {                         // symmetry: col sums
        #pragma unroll
        for (int nj = 0; nj < 4; ++nj) {
          float v = cs[nj];
          v += __shfl_xor(v, 16, 64);
          v += __shfl_xor(v, 32, 64);
          if (quad == 0)
            atomicAdd(&rowsum[rowB0 + wc * 64 + nj * 16 + l15], v);
        }
      }
    }
  }

  // strip row sums: one atomic per row per wave
  #pragma unroll
  for (int mi = 0; mi < 4; ++mi)
    #pragma unroll
    for (int r = 0; r < 4; ++r) {
      float v = rs[mi][r];
      v += __shfl_xor(v, 1, 64);
      v += __shfl_xor(v, 2, 64);
      v += __shfl_xor(v, 4, 64);
      v += __shfl_xor(v, 8, 64);
      if (l15 == 0)
        atomicAdd(&rowsum[rowA0 + wr * 64 + mi * 16 + quad * 4 + r], v);
    }
}

// ---------------- final scalar reduction (32 blocks) -----------------------
__global__ __launch_bounds__(256) void finalize_kernel(
    const float* __restrict__ rowsum, const float* __restrict__ pos,
    float* __restrict__ out) {
  __shared__ float red[4];
  int t = threadIdx.x;
  int idx = blockIdx.x * 256 + t;              // 0..8191
  float s = __logf(rowsum[idx]);
  if (idx < BROWS) s -= 2.f * pos[idx];
  #pragma unroll
  for (int off = 32; off; off >>= 1) s += __shfl_xor(s, off, 64);
  if ((t & 63) == 0) red[t >> 6] = s;
  __syncthreads();
  if (t == 0)
    atomicAdd(out, (red[0] + red[1] + red[2] + red[3]) / (float)NROWS);
}

// ---------------- launch ----------------------------------------------------
extern "C" void kernel_launch(void* const* d_in, const int* in_sizes, int n_in,
                              void* d_out, int out_size, void* d_ws, size_t ws_size,
                              hipStream_t stream) {
  const float* z1 = (const float*)d_in[0];
  const float* z2 = (const float*)d_in[1];
  char* ws = (char*)d_ws;
  bf16*  zn     = (bf16*)ws;                               // 4 MB
  float* rowsum = (float*)(ws + 4194304);                  // 32 KB
  float* pos    = (float*)(ws + 4194304 + 32768);          // 16 KB
  float* out    = (float*)d_out;

  prep_kernel<<<BROWS / 4, 256, 0, stream>>>(z1, z2, zn, pos, rowsum, out);
  dim3 grid(16, NTILE);
  simexp_kernel<<<grid, 256, 0, stream>>>(zn, rowsum);
  finalize_kernel<<<NROWS / 256, 256, 0, stream>>>(rowsum, pos, out);
}